// Round 5
// baseline (130.979 us; speedup 1.0000x reference)
//
#include <hip/hip_runtime.h>
#include <math.h>

// B=65536, D=8, H=2 (hd=4), S=15 tokens, A=20 outputs.
// R5 (= R4 fixed): packed-f16 (v_pk_fma_f16) for the per-token 8x8 matmuls and
// the layer-0 gather, via native _Float16 ext vectors (ROCm 7.2 lacks __hmax2).
// Weights pre-packed into d_ws by a setup kernel (output-pair packing, softmax
// scale folded into q-rows). Layer-1 softmax path stays f32 (scores unbounded
// across elements); all softmax sums f32.
#define EPB 16
#define BTOT 65536
#define C_SCALE 0.72134752044f  // 0.5 * log2(e)

typedef _Float16 h2 __attribute__((ext_vector_type(2)));

// d_ws h2 layout offsets
#define WQKV1 0     // 96: [c2=0..11][j=0..7], pair-rows c2<4 (q) pre-scaled by C_SCALE
#define BQKV1 96    // 12
#define WO0   108   // 32: [c2=0..3][j=0..7]
#define BO0   140   // 4
#define WL0   144   // 32
#define BL0   176   // 4
#define WO1   180   // 32
#define BO1   212   // 4
#define WL1   216   // 32
#define BL1   248   // 4  (total 252 h2 = 1008 B)

__device__ __forceinline__ float exp2_fast(float x) {
#if defined(__has_builtin)
#if __has_builtin(__builtin_amdgcn_exp2f)
  return __builtin_amdgcn_exp2f(x);
#else
  return exp2f(x);
#endif
#else
  return exp2f(x);
#endif
}

union F4H2 { float4 f; h2 h[4]; };

// packed 8->8 matmul: out2[c2] = bias2[c2] + sum_j splat(in_j) * W2[c2][j]
__device__ __forceinline__ void mm8_h2(const h2* __restrict__ wp, int woff, int boff,
                                       const h2 in2[4], h2 out2[4])
{
#pragma unroll
  for (int c2 = 0; c2 < 4; ++c2) {
    h2 acc = wp[boff + c2];
#pragma unroll
    for (int p = 0; p < 4; ++p) {
      acc += (h2)(in2[p].x) * wp[woff + c2 * 8 + 2 * p];
      acc += (h2)(in2[p].y) * wp[woff + c2 * 8 + 2 * p + 1];
    }
    out2[c2] = acc;
  }
}

__global__ void BetterBot_setup(const float* __restrict__ Wqkv1, const float* __restrict__ bqkv1,
                                const float* __restrict__ Wo0, const float* __restrict__ bo0,
                                const float* __restrict__ Wl0, const float* __restrict__ bl0,
                                const float* __restrict__ Wo1, const float* __restrict__ bo1,
                                const float* __restrict__ Wl1, const float* __restrict__ bl1,
                                h2* __restrict__ ws)
{
  const int tid = threadIdx.x;
  if (tid < 96) {
    const int c2 = tid >> 3, j = tid & 7;
    float a = Wqkv1[(2 * c2) * 8 + j], b = Wqkv1[(2 * c2 + 1) * 8 + j];
    if (c2 < 4) { a *= C_SCALE; b *= C_SCALE; }   // q rows 0..7
    ws[tid] = (h2){(_Float16)a, (_Float16)b};
  } else if (tid < 108) {
    const int c2 = tid - 96;
    float a = bqkv1[2 * c2], b = bqkv1[2 * c2 + 1];
    if (c2 < 4) { a *= C_SCALE; b *= C_SCALE; }
    ws[tid] = (h2){(_Float16)a, (_Float16)b};
  } else if (tid < 140) {
    const int k = tid - 108, c2 = k >> 3, j = k & 7;
    ws[tid] = (h2){(_Float16)Wo0[(2 * c2) * 8 + j], (_Float16)Wo0[(2 * c2 + 1) * 8 + j]};
  } else if (tid < 144) {
    const int c2 = tid - 140;
    ws[tid] = (h2){(_Float16)bo0[2 * c2], (_Float16)bo0[2 * c2 + 1]};
  } else if (tid < 176) {
    const int k = tid - 144, c2 = k >> 3, j = k & 7;
    ws[tid] = (h2){(_Float16)Wl0[(2 * c2) * 8 + j], (_Float16)Wl0[(2 * c2 + 1) * 8 + j]};
  } else if (tid < 180) {
    const int c2 = tid - 176;
    ws[tid] = (h2){(_Float16)bl0[2 * c2], (_Float16)bl0[2 * c2 + 1]};
  } else if (tid < 212) {
    const int k = tid - 180, c2 = k >> 3, j = k & 7;
    ws[tid] = (h2){(_Float16)Wo1[(2 * c2) * 8 + j], (_Float16)Wo1[(2 * c2 + 1) * 8 + j]};
  } else if (tid < 216) {
    const int c2 = tid - 212;
    ws[tid] = (h2){(_Float16)bo1[2 * c2], (_Float16)bo1[2 * c2 + 1]};
  } else if (tid < 248) {
    const int k = tid - 216, c2 = k >> 3, j = k & 7;
    ws[tid] = (h2){(_Float16)Wl1[(2 * c2) * 8 + j], (_Float16)Wl1[(2 * c2 + 1) * 8 + j]};
  } else if (tid < 252) {
    const int c2 = tid - 248;
    ws[tid] = (h2){(_Float16)bl1[2 * c2], (_Float16)bl1[2 * c2 + 1]};
  }
}

__global__ __launch_bounds__(256, 4) void BetterBot_44169443672375_kernel(
    const int* __restrict__ dice_type, const int* __restrict__ dice_star,
    const int* __restrict__ summon_lvl,
    const float* __restrict__ emb_dice, const float* __restrict__ emb_star,
    const float* __restrict__ emb_btns,
    const float* __restrict__ Wout, const float* __restrict__ bout,
    const float* __restrict__ Wqkv0, const float* __restrict__ bqkv0,
    const h2* __restrict__ wp,
    float* __restrict__ out)
{
  __shared__ __align__(16) float qkT[32][20];      // q(0..7, pre-scaled), k(8..15), pad
  __shared__ __align__(16) h2 vT[32][4];           // layer-0 v (f16 pairs)
  __shared__ __align__(16) h2 xT[32][4];           // embedding rows (f16 pairs)
  __shared__ h2 eT[32 * 33];                       // e[qi*33+ki] = (e_h0, e_h1)
  __shared__ int idxT[EPB][16];
  __shared__ __align__(16) float kvb[EPB][15][16]; // layer-1 k(0..7) v(8..15), f32

  const int tid = threadIdx.x;
  const int e = tid >> 4;       // element in block
  const int t = tid & 15;       // token (15 = pad lane)
  const int ge = blockIdx.x * EPB + e;

  // ---- phase 1: indices + qkv0/x tables (all 256 threads) ----
  int myc = 0;
  if (t < 15) {
    int c;
    if (t < 5)       c = dice_type[ge * 5 + t];
    else if (t < 10) c = 15 + dice_star[ge * 5 + (t - 5)];
    else             c = 30 + summon_lvl[ge * 5 + (t - 10)];
    idxT[e][t] = c;
    myc = c;
  }
  {
    const int c = tid >> 3;        // 0..31 table row
    const int l8 = tid & 7;        // q col l8, k col l8, v col l8
    const float* er;
    if (c < 15)      er = emb_dice + 8 * c;
    else if (c < 30) er = emb_star + 8 * (c - 15);
    else             er = emb_btns + 8 * (c - 30);
    const float4 r0 = ((const float4*)er)[0];
    const float4 r1 = ((const float4*)er)[1];
    float r[8] = {r0.x, r0.y, r0.z, r0.w, r1.x, r1.y, r1.z, r1.w};
    if (l8 < 4) xT[c][l8] = (h2){(_Float16)r[2 * l8], (_Float16)r[2 * l8 + 1]};
    float aq = bqkv0[l8], ak = bqkv0[8 + l8], av = bqkv0[16 + l8];
#pragma unroll
    for (int j = 0; j < 8; ++j) {
      aq = fmaf(r[j], Wqkv0[l8 * 8 + j], aq);
      ak = fmaf(r[j], Wqkv0[(8 + l8) * 8 + j], ak);
      av = fmaf(r[j], Wqkv0[(16 + l8) * 8 + j], av);
    }
    qkT[c][l8] = aq * C_SCALE;   // fold scale+log2e into layer-0 q
    qkT[c][8 + l8] = ak;
    const float vn = __shfl_xor(av, 1);       // partner col's v
    if ((l8 & 1) == 0) vT[c][l8 >> 1] = (h2){(_Float16)av, (_Float16)vn};
  }
  __syncthreads();

  // ---- phase 2: layer-0 exp table, 4 (qi,ki) per thread ----
  {
    const int qi = tid >> 3;
    const int ki0 = (tid & 7) * 4;
    float qv[8];
#pragma unroll
    for (int j = 0; j < 8; ++j) qv[j] = qkT[qi][j];
#pragma unroll
    for (int jj = 0; jj < 4; ++jj) {
      const int ki = ki0 + jj;
      const float* kr = &qkT[ki][8];
      float s0 = qv[0] * kr[0];
      s0 = fmaf(qv[1], kr[1], s0); s0 = fmaf(qv[2], kr[2], s0); s0 = fmaf(qv[3], kr[3], s0);
      float s1 = qv[4] * kr[4];
      s1 = fmaf(qv[5], kr[5], s1); s1 = fmaf(qv[6], kr[6], s1); s1 = fmaf(qv[7], kr[7], s1);
      eT[qi * 33 + ki] = (h2){(_Float16)exp2_fast(s0), (_Float16)exp2_fast(s1)};
    }
  }
  __syncthreads();

  // ---- layer 0 (table-driven, packed f16) + layer-1 qkv ----
  h2 x2[4];
  float q1f[8];
  if (t < 15) {
    F4H2 xx; xx.f = *(const float4*)(&xT[myc][0]);
#pragma unroll
    for (int p = 0; p < 4; ++p) x2[p] = xx.h[p];

    h2 o2[4] = {(h2)(_Float16)0.f, (h2)(_Float16)0.f, (h2)(_Float16)0.f, (h2)(_Float16)0.f};
    float sum0 = 0.f, sum1 = 0.f;
    const h2* myE = eT + myc * 33;
#pragma unroll
    for (int u = 0; u < 15; ++u) {
      const int uc = idxT[e][u];
      const h2 ee = myE[uc];
      F4H2 vv; vv.f = *(const float4*)(&vT[uc][0]);
      const h2 el = (h2)(ee.x);
      const h2 eh = (h2)(ee.y);
      o2[0] += el * vv.h[0];
      o2[1] += el * vv.h[1];
      o2[2] += eh * vv.h[2];
      o2[3] += eh * vv.h[3];
      sum0 += (float)ee.x;
      sum1 += (float)ee.y;
    }
    const float r0 = 1.0f / sum0, r1 = 1.0f / sum1;
    o2[0] *= (h2)(_Float16)r0; o2[1] *= (h2)(_Float16)r0;
    o2[2] *= (h2)(_Float16)r1; o2[3] *= (h2)(_Float16)r1;

    h2 y2[4], xn2[4], hh2[4];
    mm8_h2(wp, WO0, BO0, o2, y2);
#pragma unroll
    for (int p = 0; p < 4; ++p) xn2[p] = x2[p] + y2[p];
    mm8_h2(wp, WL0, BL0, xn2, hh2);
    const h2 z2 = (h2)(_Float16)0.f;
#pragma unroll
    for (int p = 0; p < 4; ++p) x2[p] = xn2[p] + __builtin_elementwise_max(hh2[p], z2);

    // layer-1 qkv (packed): 12 output pairs; q pair-rows pre-scaled by C_SCALE
    h2 qkv2[12];
#pragma unroll
    for (int c2 = 0; c2 < 12; ++c2) {
      h2 acc = wp[BQKV1 + c2];
#pragma unroll
      for (int p = 0; p < 4; ++p) {
        acc += (h2)(x2[p].x) * wp[WQKV1 + c2 * 8 + 2 * p];
        acc += (h2)(x2[p].y) * wp[WQKV1 + c2 * 8 + 2 * p + 1];
      }
      qkv2[c2] = acc;
    }
#pragma unroll
    for (int p = 0; p < 4; ++p) {
      q1f[2 * p] = (float)qkv2[p].x;
      q1f[2 * p + 1] = (float)qkv2[p].y;
    }
    *(float4*)(&kvb[e][t][0]) = make_float4((float)qkv2[4].x, (float)qkv2[4].y,
                                            (float)qkv2[5].x, (float)qkv2[5].y);
    *(float4*)(&kvb[e][t][4]) = make_float4((float)qkv2[6].x, (float)qkv2[6].y,
                                            (float)qkv2[7].x, (float)qkv2[7].y);
    *(float4*)(&kvb[e][t][8]) = make_float4((float)qkv2[8].x, (float)qkv2[8].y,
                                            (float)qkv2[9].x, (float)qkv2[9].y);
    *(float4*)(&kvb[e][t][12]) = make_float4((float)qkv2[10].x, (float)qkv2[10].y,
                                             (float)qkv2[11].x, (float)qkv2[11].y);
  }
  __syncthreads();

  // ---- layer 1: f32 fused no-max softmax + attnV, f16 epilogue matmuls ----
  float xo[8] = {0.f, 0.f, 0.f, 0.f, 0.f, 0.f, 0.f, 0.f};
  if (t < 15) {
    float o[8] = {0.f, 0.f, 0.f, 0.f, 0.f, 0.f, 0.f, 0.f};
    float sum0 = 0.f, sum1 = 0.f;
#pragma unroll
    for (int u = 0; u < 15; ++u) {
      const float4 ka = *(const float4*)(&kvb[e][u][0]);
      const float4 kb2 = *(const float4*)(&kvb[e][u][4]);
      const float4 va = *(const float4*)(&kvb[e][u][8]);
      const float4 vb2 = *(const float4*)(&kvb[e][u][12]);
      float s0 = q1f[0] * ka.x;
      s0 = fmaf(q1f[1], ka.y, s0); s0 = fmaf(q1f[2], ka.z, s0); s0 = fmaf(q1f[3], ka.w, s0);
      float s1 = q1f[4] * kb2.x;
      s1 = fmaf(q1f[5], kb2.y, s1); s1 = fmaf(q1f[6], kb2.z, s1); s1 = fmaf(q1f[7], kb2.w, s1);
      const float e0 = exp2_fast(s0);
      const float e1 = exp2_fast(s1);
      sum0 += e0; sum1 += e1;
      o[0] = fmaf(e0, va.x, o[0]); o[1] = fmaf(e0, va.y, o[1]);
      o[2] = fmaf(e0, va.z, o[2]); o[3] = fmaf(e0, va.w, o[3]);
      o[4] = fmaf(e1, vb2.x, o[4]); o[5] = fmaf(e1, vb2.y, o[5]);
      o[6] = fmaf(e1, vb2.z, o[6]); o[7] = fmaf(e1, vb2.w, o[7]);
    }
    const float r0 = 1.0f / sum0, r1 = 1.0f / sum1;
    h2 po2[4];
    po2[0] = (h2){(_Float16)(o[0] * r0), (_Float16)(o[1] * r0)};
    po2[1] = (h2){(_Float16)(o[2] * r0), (_Float16)(o[3] * r0)};
    po2[2] = (h2){(_Float16)(o[4] * r1), (_Float16)(o[5] * r1)};
    po2[3] = (h2){(_Float16)(o[6] * r1), (_Float16)(o[7] * r1)};

    h2 y2[4], xn2[4], hh2[4];
    mm8_h2(wp, WO1, BO1, po2, y2);
#pragma unroll
    for (int p = 0; p < 4; ++p) xn2[p] = x2[p] + y2[p];
    mm8_h2(wp, WL1, BL1, xn2, hh2);
    const h2 z2 = (h2)(_Float16)0.f;
#pragma unroll
    for (int p = 0; p < 4; ++p) {
      const h2 xf = xn2[p] + __builtin_elementwise_max(hh2[p], z2);
      xo[2 * p] = (float)xf.x;
      xo[2 * p + 1] = (float)xf.y;
    }
  }

  // ---- epilogue: mean via 16-lane shfl butterfly (f32), then head ----
  float p[8];
#pragma unroll
  for (int j = 0; j < 8; ++j) p[j] = xo[j];
#pragma unroll
  for (int j = 0; j < 8; ++j) p[j] += __shfl_xor(p[j], 1);
#pragma unroll
  for (int j = 0; j < 8; ++j) p[j] += __shfl_xor(p[j], 2);
#pragma unroll
  for (int j = 0; j < 8; ++j) p[j] += __shfl_xor(p[j], 4);
#pragma unroll
  for (int j = 0; j < 8; ++j) p[j] += __shfl_xor(p[j], 8);
  float mean[8];
#pragma unroll
  for (int j = 0; j < 8; ++j) mean[j] = p[j] * (1.0f / 15.0f);

  const int obase = ge * 20;
  {
    float acc = bout[t];
#pragma unroll
    for (int j = 0; j < 8; ++j) acc = fmaf(mean[j], Wout[t * 8 + j], acc);
    out[obase + t] = acc;               // a = 0..15
  }
  if (t < 4) {
    const int a = 16 + t;
    float acc = bout[a];
#pragma unroll
    for (int j = 0; j < 8; ++j) acc = fmaf(mean[j], Wout[a * 8 + j], acc);
    out[obase + a] = acc;               // a = 16..19
  }
}

extern "C" void kernel_launch(void* const* d_in, const int* in_sizes, int n_in,
                              void* d_out, int out_size, void* d_ws, size_t ws_size,
                              hipStream_t stream) {
  const int*   dice_type  = (const int*)d_in[0];
  const int*   dice_star  = (const int*)d_in[1];
  const int*   summon_lvl = (const int*)d_in[2];
  const float* emb_dice   = (const float*)d_in[3];
  const float* emb_star   = (const float*)d_in[4];
  const float* emb_btns   = (const float*)d_in[5];
  const float* Wout       = (const float*)d_in[6];
  const float* bout       = (const float*)d_in[7];
  const float* Wqkv0      = (const float*)d_in[8];
  const float* bqkv0      = (const float*)d_in[9];
  const float* Wo0        = (const float*)d_in[10];
  const float* bo0        = (const float*)d_in[11];
  const float* Wl0        = (const float*)d_in[12];
  const float* bl0        = (const float*)d_in[13];
  const float* Wqkv1      = (const float*)d_in[14];
  const float* bqkv1      = (const float*)d_in[15];
  const float* Wo1        = (const float*)d_in[16];
  const float* bo1        = (const float*)d_in[17];
  const float* Wl1        = (const float*)d_in[18];
  const float* bl1        = (const float*)d_in[19];
  float* out = (float*)d_out;
  h2* ws = (h2*)d_ws;

  hipLaunchKernelGGL(BetterBot_setup, dim3(1), dim3(256), 0, stream,
                     Wqkv1, bqkv1, Wo0, bo0, Wl0, bl0, Wo1, bo1, Wl1, bl1, ws);
  hipLaunchKernelGGL(BetterBot_44169443672375_kernel, dim3(BTOT / EPB), dim3(256), 0, stream,
                     dice_type, dice_star, summon_lvl,
                     emb_dice, emb_star, emb_btns, Wout, bout,
                     Wqkv0, bqkv0, (const h2*)ws, out);
}

// Round 8
// 126.938 us; speedup vs baseline: 1.0318x; 1.0318x over previous
//
#include <hip/hip_runtime.h>
#include <math.h>

// B=65536, D=8, H=2 (hd=4), S=15 tokens, A=20 outputs.
// R8: R7 minus f16-overflow hazards. fdot2 f16 scores everywhere; layer-0 PV
// pk-f16 (R5-proven bounded), layer-0 softmax sums f32 via fdot2(e,(1,0));
// layer-1 exp/sums/PV all f32 (scores unbounded), v kept f32 in kvb in
// permuted (head-interleaved) order so normalized o packs directly into the
// interleaved layout feeding column-reordered WO1. f32 epilogue butterfly.
#define EPB 16
#define BTOT 65536
#define C_SCALE 0.72134752044f  // 0.5 * log2(e)

typedef _Float16 h2 __attribute__((ext_vector_type(2)));
typedef __fp16 fp16v2 __attribute__((ext_vector_type(2)));

// d_ws h2 layout offsets
#define WQKV1 0     // 96: [c2=0..11][j pairs]; q rows (2c,2c+1)*C_SCALE, k rows seq (v part unused)
#define BQKV1 96    // 12 (v part unused)
#define WO0   108   // 32: cols reordered (p, p+4) for interleaved-o input
#define BO0   140   // 4
#define WL0   144   // 32: natural
#define BL0   176   // 4
#define WO1   180   // 32: cols reordered
#define BO1   212   // 4
#define WL1   216   // 32: natural
#define BL1   248   // 4
#define WV1P  256   // 32: [r=0..7][p=0..3] = (Wv[perm[r]][2p], Wv[perm[r]][2p+1]); perm=(r>>1)+(r&1)*4
#define BV1F  288   // 8 floats (f32!) = bv[perm[r]]

__device__ __forceinline__ float exp2_fast(float x) { return __builtin_amdgcn_exp2f(x); }
__device__ __forceinline__ float rcp_fast(float x)  { return __builtin_amdgcn_rcpf(x); }
__device__ __forceinline__ h2 pkrtz(float a, float b) {
  fp16v2 r = __builtin_amdgcn_cvt_pkrtz(a, b);
  return __builtin_bit_cast(h2, r);
}
__device__ __forceinline__ float fdot2f(h2 a, h2 b, float c) {
#if defined(__has_builtin) && __has_builtin(__builtin_amdgcn_fdot2)
  return __builtin_amdgcn_fdot2(a, b, c, false);
#else
  return (float)a.x * (float)b.x + (float)a.y * (float)b.y + c;
#endif
}

union F4H2 { float4 f; h2 h[4]; };

// packed 8->8 matmul: out2[c2] = bias2[c2] + sum_p splat(in[p].x)*W2[c2][2p] + splat(in[p].y)*W2[c2][2p+1]
__device__ __forceinline__ void mm8_h2(const h2* __restrict__ wp, int woff, int boff,
                                       const h2 in2[4], h2 out2[4])
{
#pragma unroll
  for (int c2 = 0; c2 < 4; ++c2) {
    h2 acc = wp[boff + c2];
#pragma unroll
    for (int p = 0; p < 4; ++p) {
      acc += (h2)(in2[p].x) * wp[woff + c2 * 8 + 2 * p];
      acc += (h2)(in2[p].y) * wp[woff + c2 * 8 + 2 * p + 1];
    }
    out2[c2] = acc;
  }
}

__global__ void BetterBot_setup(const float* __restrict__ Wqkv1, const float* __restrict__ bqkv1,
                                const float* __restrict__ Wo0, const float* __restrict__ bo0,
                                const float* __restrict__ Wl0, const float* __restrict__ bl0,
                                const float* __restrict__ Wo1, const float* __restrict__ bo1,
                                const float* __restrict__ Wl1, const float* __restrict__ bl1,
                                h2* __restrict__ ws)
{
  const int tid = threadIdx.x;
  if (tid < 96) {
    const int c2 = tid >> 3, j = tid & 7;
    int ra, rb; float s = 1.0f;
    if (c2 < 4)      { ra = 2 * c2; rb = ra + 1; s = C_SCALE; }      // q seq pairs, scaled
    else if (c2 < 8) { ra = 8 + 2 * (c2 - 4); rb = ra + 1; }          // k seq pairs
    else             { ra = 16 + (c2 - 8); rb = ra + 4; }             // (unused)
    ws[tid] = pkrtz(Wqkv1[ra * 8 + j] * s, Wqkv1[rb * 8 + j] * s);
  } else if (tid < 108) {
    const int c2 = tid - 96;
    int ra, rb; float s = 1.0f;
    if (c2 < 4)      { ra = 2 * c2; rb = ra + 1; s = C_SCALE; }
    else if (c2 < 8) { ra = 8 + 2 * (c2 - 4); rb = ra + 1; }
    else             { ra = 16 + (c2 - 8); rb = ra + 4; }
    ws[tid] = pkrtz(bqkv1[ra] * s, bqkv1[rb] * s);
  } else if (tid < 140) {          // WO0, cols reordered for interleaved-o
    const int k = tid - 108, c2 = k >> 3, j = k & 7, p = j >> 1;
    const int col = (j & 1) ? (p + 4) : p;
    ws[tid] = pkrtz(Wo0[(2 * c2) * 8 + col], Wo0[(2 * c2 + 1) * 8 + col]);
  } else if (tid < 144) {
    const int c2 = tid - 140;
    ws[tid] = pkrtz(bo0[2 * c2], bo0[2 * c2 + 1]);
  } else if (tid < 176) {          // WL0 natural
    const int k = tid - 144, c2 = k >> 3, j = k & 7;
    ws[tid] = pkrtz(Wl0[(2 * c2) * 8 + j], Wl0[(2 * c2 + 1) * 8 + j]);
  } else if (tid < 180) {
    const int c2 = tid - 176;
    ws[tid] = pkrtz(bl0[2 * c2], bl0[2 * c2 + 1]);
  } else if (tid < 212) {          // WO1, cols reordered
    const int k = tid - 180, c2 = k >> 3, j = k & 7, p = j >> 1;
    const int col = (j & 1) ? (p + 4) : p;
    ws[tid] = pkrtz(Wo1[(2 * c2) * 8 + col], Wo1[(2 * c2 + 1) * 8 + col]);
  } else if (tid < 216) {
    const int c2 = tid - 212;
    ws[tid] = pkrtz(bo1[2 * c2], bo1[2 * c2 + 1]);
  } else if (tid < 248) {          // WL1 natural
    const int k = tid - 216, c2 = k >> 3, j = k & 7;
    ws[tid] = pkrtz(Wl1[(2 * c2) * 8 + j], Wl1[(2 * c2 + 1) * 8 + j]);
  } else if (tid < 252) {
    const int c2 = tid - 248;
    ws[tid] = pkrtz(bl1[2 * c2], bl1[2 * c2 + 1]);
  }
  // layer-1 v weights (pair-packed, rows permuted) + f32 biases
  if (tid < 32) {
    const int r = tid >> 2, p = tid & 3;
    const int row = 16 + (r >> 1) + (r & 1) * 4;   // perm: v0,v4,v1,v5,v2,v6,v3,v7
    ws[WV1P + tid] = pkrtz(Wqkv1[row * 8 + 2 * p], Wqkv1[row * 8 + 2 * p + 1]);
  } else if (tid < 40) {
    const int r = tid - 32;
    const int row = 16 + (r >> 1) + (r & 1) * 4;
    ((float*)(ws + BV1F))[r] = bqkv1[row];
  }
}

__global__ __launch_bounds__(256, 8) void BetterBot_44169443672375_kernel(
    const int* __restrict__ dice_type, const int* __restrict__ dice_star,
    const int* __restrict__ summon_lvl,
    const float* __restrict__ emb_dice, const float* __restrict__ emb_star,
    const float* __restrict__ emb_btns,
    const float* __restrict__ Wout, const float* __restrict__ bout,
    const float* __restrict__ Wqkv0, const float* __restrict__ bqkv0,
    const h2* __restrict__ wp,
    float* __restrict__ out)
{
  __shared__ __align__(16) h2 qT16[32][4];    // layer-0 q, seq pairs, C_SCALE folded
  __shared__ __align__(16) h2 kT16[32][4];    // layer-0 k, seq pairs
  __shared__ __align__(16) h2 vT[32][4];      // layer-0 v, head-interleaved pairs
  __shared__ __align__(16) h2 xT[32][4];      // embedding rows, seq pairs
  __shared__ h2 eT[32 * 33];                  // e[qi*33+ki] = (e_h0, e_h1)
  __shared__ int idxT[EPB][16];
  __shared__ __align__(16) float kvb[EPB][15][12]; // [k f16 pairs (4 slots) | v f32 permuted (8)]

  const int tid = threadIdx.x;
  const int e = tid >> 4;       // element in block
  const int t = tid & 15;       // token (15 = pad lane)
  const int ge = blockIdx.x * EPB + e;
  const float* wsf = (const float*)(wp + BV1F);

  // ---- phase 1: indices + layer-0 qkv/x tables (all 256 threads) ----
  int myc = 0;
  if (t < 15) {
    int c;
    if (t < 5)       c = dice_type[ge * 5 + t];
    else if (t < 10) c = 15 + dice_star[ge * 5 + (t - 5)];
    else             c = 30 + summon_lvl[ge * 5 + (t - 10)];
    idxT[e][t] = c;
    myc = c;
  }
  {
    const int c = tid >> 3;        // 0..31 table row
    const int l8 = tid & 7;        // this thread computes column l8 of q,k,v
    const float* er;
    if (c < 15)      er = emb_dice + 8 * c;
    else if (c < 30) er = emb_star + 8 * (c - 15);
    else             er = emb_btns + 8 * (c - 30);
    const float4 r0 = ((const float4*)er)[0];
    const float4 r1 = ((const float4*)er)[1];
    float r[8] = {r0.x, r0.y, r0.z, r0.w, r1.x, r1.y, r1.z, r1.w};
    if (l8 < 4) xT[c][l8] = pkrtz(r[2 * l8], r[2 * l8 + 1]);
    float aq = bqkv0[l8], ak = bqkv0[8 + l8], av = bqkv0[16 + l8];
#pragma unroll
    for (int j = 0; j < 8; ++j) {
      aq = fmaf(r[j], Wqkv0[l8 * 8 + j], aq);
      ak = fmaf(r[j], Wqkv0[(8 + l8) * 8 + j], ak);
      av = fmaf(r[j], Wqkv0[(16 + l8) * 8 + j], av);
    }
    aq *= C_SCALE;
    const float aq_p = __shfl_xor(aq, 1);   // seq-pair partner (col l8+1)
    const float ak_p = __shfl_xor(ak, 1);
    const float av_p = __shfl_xor(av, 4);   // interleave partner (col l8+4)
    if ((l8 & 1) == 0) {
      qT16[c][l8 >> 1] = pkrtz(aq, aq_p);
      kT16[c][l8 >> 1] = pkrtz(ak, ak_p);
    }
    if (l8 < 4) vT[c][l8] = pkrtz(av, av_p);
  }
  __syncthreads();

  // ---- phase 2: layer-0 exp table; ki = l8 + 8*jj keeps b128 reads conflict-free ----
  {
    const int qi = tid >> 3;
    const int l8 = tid & 7;
    F4H2 qr; qr.f = *(const float4*)(&qT16[qi][0]);
#pragma unroll
    for (int jj = 0; jj < 4; ++jj) {
      const int ki = l8 + 8 * jj;
      F4H2 kr; kr.f = *(const float4*)(&kT16[ki][0]);
      const float s0 = fdot2f(qr.h[0], kr.h[0], fdot2f(qr.h[1], kr.h[1], 0.f));
      const float s1 = fdot2f(qr.h[2], kr.h[2], fdot2f(qr.h[3], kr.h[3], 0.f));
      eT[qi * 33 + ki] = pkrtz(exp2_fast(s0), exp2_fast(s1));
    }
  }
  __syncthreads();

  // ---- layer 0 (table-driven pk) + layer-1 qkv ----
  h2 x2[4] = {(h2)(_Float16)0.f, (h2)(_Float16)0.f, (h2)(_Float16)0.f, (h2)(_Float16)0.f};
  h2 q2[4];
  const h2 ONE0 = {(_Float16)1.f, (_Float16)0.f};
  const h2 ONE1 = {(_Float16)0.f, (_Float16)1.f};
  if (t < 15) {
    F4H2 xx; xx.f = *(const float4*)(&xT[myc][0]);
#pragma unroll
    for (int p = 0; p < 4; ++p) x2[p] = xx.h[p];

    h2 o2[4] = {(h2)(_Float16)0.f, (h2)(_Float16)0.f, (h2)(_Float16)0.f, (h2)(_Float16)0.f};
    float sum0 = 0.f, sum1 = 0.f;   // f32 sums (overflow-safe)
    const h2* myE = eT + myc * 33;
#pragma unroll
    for (int u = 0; u < 15; ++u) {
      const int uc = idxT[e][u];
      const h2 ee2 = myE[uc];                  // (e_h0, e_h1)
      F4H2 vv; vv.f = *(const float4*)(&vT[uc][0]);
      sum0 = fdot2f(ee2, ONE0, sum0);
      sum1 = fdot2f(ee2, ONE1, sum1);
      o2[0] += ee2 * vv.h[0];
      o2[1] += ee2 * vv.h[1];
      o2[2] += ee2 * vv.h[2];
      o2[3] += ee2 * vv.h[3];
    }
    const h2 rp2 = pkrtz(rcp_fast(sum0), rcp_fast(sum1));
#pragma unroll
    for (int p = 0; p < 4; ++p) o2[p] *= rp2;  // per-head normalize (interleaved)

    h2 y2[4], xn2[4], hh2[4];
    mm8_h2(wp, WO0, BO0, o2, y2);              // cols pre-reordered for interleaved o
#pragma unroll
    for (int p = 0; p < 4; ++p) xn2[p] = x2[p] + y2[p];
    mm8_h2(wp, WL0, BL0, xn2, hh2);
    const h2 z2 = (h2)(_Float16)0.f;
#pragma unroll
    for (int p = 0; p < 4; ++p) x2[p] = xn2[p] + __builtin_elementwise_max(hh2[p], z2);

    // layer-1 q,k (pk-f16): 8 output pairs; q pair-rows pre-scaled
    h2 qkv2[8];
#pragma unroll
    for (int c2 = 0; c2 < 8; ++c2) {
      h2 acc = wp[BQKV1 + c2];
#pragma unroll
      for (int p = 0; p < 4; ++p) {
        acc += (h2)(x2[p].x) * wp[WQKV1 + c2 * 8 + 2 * p];
        acc += (h2)(x2[p].y) * wp[WQKV1 + c2 * 8 + 2 * p + 1];
      }
      qkv2[c2] = acc;
    }
#pragma unroll
    for (int p = 0; p < 4; ++p) q2[p] = qkv2[p];
    // layer-1 v (f32 via fdot2, rows pre-permuted v0,v4,v1,v5,v2,v6,v3,v7)
    float vv[8];
#pragma unroll
    for (int r = 0; r < 8; ++r) {
      float acc = wsf[r];
#pragma unroll
      for (int p = 0; p < 4; ++p) acc = fdot2f(x2[p], wp[WV1P + r * 4 + p], acc);
      vv[r] = acc;
    }
    F4H2 ka;
#pragma unroll
    for (int p = 0; p < 4; ++p) ka.h[p] = qkv2[4 + p];
    *(float4*)(&kvb[e][t][0]) = ka.f;
    *(float4*)(&kvb[e][t][4]) = make_float4(vv[0], vv[1], vv[2], vv[3]);
    *(float4*)(&kvb[e][t][8]) = make_float4(vv[4], vv[5], vv[6], vv[7]);
  }
  __syncthreads();

  // ---- layer 1: fdot2 f16 scores, f32 exp/sums/PV (overflow-safe) ----
  if (t < 15) {
    float o[8] = {0.f, 0.f, 0.f, 0.f, 0.f, 0.f, 0.f, 0.f};  // permuted order
    float sum0 = 0.f, sum1 = 0.f;
#pragma unroll
    for (int u = 0; u < 15; ++u) {
      F4H2 kk; kk.f = *(const float4*)(&kvb[e][u][0]);
      const float4 va = *(const float4*)(&kvb[e][u][4]);
      const float4 vb = *(const float4*)(&kvb[e][u][8]);
      const float s0 = fdot2f(q2[0], kk.h[0], fdot2f(q2[1], kk.h[1], 0.f));
      const float s1 = fdot2f(q2[2], kk.h[2], fdot2f(q2[3], kk.h[3], 0.f));
      const float e0 = exp2_fast(s0);
      const float e1 = exp2_fast(s1);
      sum0 += e0; sum1 += e1;
      o[0] = fmaf(e0, va.x, o[0]); o[1] = fmaf(e1, va.y, o[1]);
      o[2] = fmaf(e0, va.z, o[2]); o[3] = fmaf(e1, va.w, o[3]);
      o[4] = fmaf(e0, vb.x, o[4]); o[5] = fmaf(e1, vb.y, o[5]);
      o[6] = fmaf(e0, vb.z, o[6]); o[7] = fmaf(e1, vb.w, o[7]);
    }
    const float r0 = rcp_fast(sum0), r1 = rcp_fast(sum1);
    h2 po2[4];
#pragma unroll
    for (int i = 0; i < 4; ++i) po2[i] = pkrtz(o[2 * i] * r0, o[2 * i + 1] * r1);

    h2 y2[4], xn2[4], hh2[4];
    mm8_h2(wp, WO1, BO1, po2, y2);             // cols pre-reordered for interleaved o
#pragma unroll
    for (int p = 0; p < 4; ++p) xn2[p] = x2[p] + y2[p];
    mm8_h2(wp, WL1, BL1, xn2, hh2);
    const h2 z2 = (h2)(_Float16)0.f;
#pragma unroll
    for (int p = 0; p < 4; ++p) x2[p] = xn2[p] + __builtin_elementwise_max(hh2[p], z2);
  } else {
#pragma unroll
    for (int p = 0; p < 4; ++p) x2[p] = (h2)(_Float16)0.f;  // pad lane contributes 0
  }

  // ---- epilogue: mean via f32 16-lane shfl butterfly, then head ----
  float p[8];
#pragma unroll
  for (int i = 0; i < 4; ++i) { p[2 * i] = (float)x2[i].x; p[2 * i + 1] = (float)x2[i].y; }
#pragma unroll
  for (int j = 0; j < 8; ++j) p[j] += __shfl_xor(p[j], 1);
#pragma unroll
  for (int j = 0; j < 8; ++j) p[j] += __shfl_xor(p[j], 2);
#pragma unroll
  for (int j = 0; j < 8; ++j) p[j] += __shfl_xor(p[j], 4);
#pragma unroll
  for (int j = 0; j < 8; ++j) p[j] += __shfl_xor(p[j], 8);
  float mean[8];
#pragma unroll
  for (int j = 0; j < 8; ++j) mean[j] = p[j] * (1.0f / 15.0f);

  const int obase = ge * 20;
  {
    float acc = bout[t];
#pragma unroll
    for (int j = 0; j < 8; ++j) acc = fmaf(mean[j], Wout[t * 8 + j], acc);
    out[obase + t] = acc;               // a = 0..15
  }
  if (t < 4) {
    const int a = 16 + t;
    float acc = bout[a];
#pragma unroll
    for (int j = 0; j < 8; ++j) acc = fmaf(mean[j], Wout[a * 8 + j], acc);
    out[obase + a] = acc;               // a = 16..19
  }
}

extern "C" void kernel_launch(void* const* d_in, const int* in_sizes, int n_in,
                              void* d_out, int out_size, void* d_ws, size_t ws_size,
                              hipStream_t stream) {
  const int*   dice_type  = (const int*)d_in[0];
  const int*   dice_star  = (const int*)d_in[1];
  const int*   summon_lvl = (const int*)d_in[2];
  const float* emb_dice   = (const float*)d_in[3];
  const float* emb_star   = (const float*)d_in[4];
  const float* emb_btns   = (const float*)d_in[5];
  const float* Wout       = (const float*)d_in[6];
  const float* bout       = (const float*)d_in[7];
  const float* Wqkv0      = (const float*)d_in[8];
  const float* bqkv0      = (const float*)d_in[9];
  const float* Wo0        = (const float*)d_in[10];
  const float* bo0        = (const float*)d_in[11];
  const float* Wl0        = (const float*)d_in[12];
  const float* bl0        = (const float*)d_in[13];
  const float* Wqkv1      = (const float*)d_in[14];
  const float* bqkv1      = (const float*)d_in[15];
  const float* Wo1        = (const float*)d_in[16];
  const float* bo1        = (const float*)d_in[17];
  const float* Wl1        = (const float*)d_in[18];
  const float* bl1        = (const float*)d_in[19];
  float* out = (float*)d_out;
  h2* ws = (h2*)d_ws;

  hipLaunchKernelGGL(BetterBot_setup, dim3(1), dim3(256), 0, stream,
                     Wqkv1, bqkv1, Wo0, bo0, Wl0, bl0, Wo1, bo1, Wl1, bl1, ws);
  hipLaunchKernelGGL(BetterBot_44169443672375_kernel, dim3(BTOT / EPB), dim3(256), 0, stream,
                     dice_type, dice_star, summon_lvl,
                     emb_dice, emb_star, emb_btns, Wout, bout,
                     Wqkv0, bqkv0, (const h2*)ws, out);
}

// Round 9
// 123.166 us; speedup vs baseline: 1.0634x; 1.0306x over previous
//
#include <hip/hip_runtime.h>
#include <math.h>

// B=65536, D=8, H=2 (hd=4), S=15 tokens, A=20 outputs.
// R9: hoist the block-invariant layer-0 tables (qkv0-derived exp table 32x33,
// v table, x table) into the one-block setup kernel -> d_ws; main kernel does
// a 5.2KB global->LDS copy instead of recomputing them per block (removes
// phase-2 + one barrier). Layer-0 softmax sums via pk-add of e-pairs (f16-safe:
// table e bounded). 1/15 folded into Wout' in d_ws. h2 epilogue butterfly.
// Layer-1 numerics identical to R8 (proven): f16 fdot2 scores, f32 exp/sum/PV,
// v f32 permuted in kvb, interleaved po2 -> column-reordered WO1.
#define EPB 16
#define BTOT 65536
#define C_SCALE 0.72134752044f  // 0.5 * log2(e)

typedef _Float16 h2 __attribute__((ext_vector_type(2)));
typedef __fp16 fp16v2 __attribute__((ext_vector_type(2)));

// d_ws h2 layout offsets (h2 = 4B, same index granularity as float)
#define WQKV1 0     // 96: [c2=0..11][j pairs]; q rows (2c,2c+1)*C_SCALE, k rows seq
#define BQKV1 96    // 12
#define WO0   108   // 32: cols reordered (p, p+4) for interleaved-o input
#define BO0   140   // 4
#define WL0   144   // 32: natural
#define BL0   176   // 4
#define WO1   180   // 32: cols reordered
#define BO1   212   // 4
#define WL1   216   // 32: natural
#define BL1   248   // 4
#define WV1P  256   // 32: [r=0..7][p=0..3]; rows permuted v0,v4,v1,v5,v2,v6,v3,v7
#define BV1F  288   // 8 f32 biases (permuted)
#define XT    304   // 128: x rows, seq pairs
#define VT    432   // 128: layer-0 v rows, head-interleaved pairs (stride 4)
#define ET    560   // 1056: e[qi*33+ki] = (e_h0, e_h1) f16
#define WOUTF 1616  // 160 f32: Wout/15, [a][j]
#define BOUTF 1776  // 20 f32: bout
// main-kernel LDS table copy: h2 [304,1616) = 1312 h2 = 328 float4
#define TBL0  304
#define TBLV4 328
// offsets inside the LDS copy (h2 units)
#define XTO 0
#define VTO 128
#define ETO 256

__device__ __forceinline__ float exp2_fast(float x) { return __builtin_amdgcn_exp2f(x); }
__device__ __forceinline__ float rcp_fast(float x)  { return __builtin_amdgcn_rcpf(x); }
__device__ __forceinline__ h2 pkrtz(float a, float b) {
  fp16v2 r = __builtin_amdgcn_cvt_pkrtz(a, b);
  return __builtin_bit_cast(h2, r);
}
__device__ __forceinline__ float fdot2f(h2 a, h2 b, float c) {
#if defined(__has_builtin) && __has_builtin(__builtin_amdgcn_fdot2)
  return __builtin_amdgcn_fdot2(a, b, c, false);
#else
  return (float)a.x * (float)b.x + (float)a.y * (float)b.y + c;
#endif
}

union F4H2 { float4 f; h2 h[4]; };
union H2I { h2 h; int i; };

__device__ __forceinline__ void mm8_h2(const h2* __restrict__ wp, int woff, int boff,
                                       const h2 in2[4], h2 out2[4])
{
#pragma unroll
  for (int c2 = 0; c2 < 4; ++c2) {
    h2 acc = wp[boff + c2];
#pragma unroll
    for (int p = 0; p < 4; ++p) {
      acc += (h2)(in2[p].x) * wp[woff + c2 * 8 + 2 * p];
      acc += (h2)(in2[p].y) * wp[woff + c2 * 8 + 2 * p + 1];
    }
    out2[c2] = acc;
  }
}

__global__ void BetterBot_setup(
    const float* __restrict__ emb_dice, const float* __restrict__ emb_star,
    const float* __restrict__ emb_btns,
    const float* __restrict__ Wout, const float* __restrict__ bout,
    const float* __restrict__ Wqkv0, const float* __restrict__ bqkv0,
    const float* __restrict__ Wqkv1, const float* __restrict__ bqkv1,
    const float* __restrict__ Wo0, const float* __restrict__ bo0,
    const float* __restrict__ Wl0, const float* __restrict__ bl0,
    const float* __restrict__ Wo1, const float* __restrict__ bo1,
    const float* __restrict__ Wl1, const float* __restrict__ bl1,
    h2* __restrict__ ws)
{
  __shared__ float qs[32][8], ks[32][8], vs[32][8];
  const int tid = threadIdx.x;
  float* wsf = (float*)ws;

  // ---- weight packing (R8-proven) ----
  if (tid < 96) {
    const int c2 = tid >> 3, j = tid & 7;
    int ra, rb; float s = 1.0f;
    if (c2 < 4)      { ra = 2 * c2; rb = ra + 1; s = C_SCALE; }
    else if (c2 < 8) { ra = 8 + 2 * (c2 - 4); rb = ra + 1; }
    else             { ra = 16 + (c2 - 8); rb = ra + 4; }
    ws[tid] = pkrtz(Wqkv1[ra * 8 + j] * s, Wqkv1[rb * 8 + j] * s);
  } else if (tid < 108) {
    const int c2 = tid - 96;
    int ra, rb; float s = 1.0f;
    if (c2 < 4)      { ra = 2 * c2; rb = ra + 1; s = C_SCALE; }
    else if (c2 < 8) { ra = 8 + 2 * (c2 - 4); rb = ra + 1; }
    else             { ra = 16 + (c2 - 8); rb = ra + 4; }
    ws[tid] = pkrtz(bqkv1[ra] * s, bqkv1[rb] * s);
  } else if (tid < 140) {
    const int k = tid - 108, c2 = k >> 3, j = k & 7, p = j >> 1;
    const int col = (j & 1) ? (p + 4) : p;
    ws[tid] = pkrtz(Wo0[(2 * c2) * 8 + col], Wo0[(2 * c2 + 1) * 8 + col]);
  } else if (tid < 144) {
    const int c2 = tid - 140;
    ws[tid] = pkrtz(bo0[2 * c2], bo0[2 * c2 + 1]);
  } else if (tid < 176) {
    const int k = tid - 144, c2 = k >> 3, j = k & 7;
    ws[tid] = pkrtz(Wl0[(2 * c2) * 8 + j], Wl0[(2 * c2 + 1) * 8 + j]);
  } else if (tid < 180) {
    const int c2 = tid - 176;
    ws[tid] = pkrtz(bl0[2 * c2], bl0[2 * c2 + 1]);
  } else if (tid < 212) {
    const int k = tid - 180, c2 = k >> 3, j = k & 7, p = j >> 1;
    const int col = (j & 1) ? (p + 4) : p;
    ws[tid] = pkrtz(Wo1[(2 * c2) * 8 + col], Wo1[(2 * c2 + 1) * 8 + col]);
  } else if (tid < 216) {
    const int c2 = tid - 212;
    ws[tid] = pkrtz(bo1[2 * c2], bo1[2 * c2 + 1]);
  } else if (tid < 248) {
    const int k = tid - 216, c2 = k >> 3, j = k & 7;
    ws[tid] = pkrtz(Wl1[(2 * c2) * 8 + j], Wl1[(2 * c2 + 1) * 8 + j]);
  } else if (tid < 252) {
    const int c2 = tid - 248;
    ws[tid] = pkrtz(bl1[2 * c2], bl1[2 * c2 + 1]);
  }
  if (tid < 32) {
    const int r = tid >> 2, p = tid & 3;
    const int row = 16 + (r >> 1) + (r & 1) * 4;   // perm: v0,v4,v1,v5,v2,v6,v3,v7
    ws[WV1P + tid] = pkrtz(Wqkv1[row * 8 + 2 * p], Wqkv1[row * 8 + 2 * p + 1]);
  } else if (tid < 40) {
    const int r = tid - 32;
    const int row = 16 + (r >> 1) + (r & 1) * 4;
    wsf[BV1F + r] = bqkv1[row];
  }
  // head weights with 1/15 folded
  if (tid < 160)      wsf[WOUTF + tid] = Wout[tid] * (1.0f / 15.0f);
  else if (tid < 180) wsf[BOUTF + tid - 160] = bout[tid - 160];

  // ---- stage A: layer-0 qkv table (32 rows x 8 cols, one col/thread) ----
  {
    const int c = tid >> 3, l8 = tid & 7;
    const float* er;
    if (c < 15)      er = emb_dice + 8 * c;
    else if (c < 30) er = emb_star + 8 * (c - 15);
    else             er = emb_btns + 8 * (c - 30);
    const float4 r0 = ((const float4*)er)[0];
    const float4 r1 = ((const float4*)er)[1];
    float r[8] = {r0.x, r0.y, r0.z, r0.w, r1.x, r1.y, r1.z, r1.w};
    if (l8 < 4) ws[XT + c * 4 + l8] = pkrtz(r[2 * l8], r[2 * l8 + 1]);
    float aq = bqkv0[l8], ak = bqkv0[8 + l8], av = bqkv0[16 + l8];
#pragma unroll
    for (int j = 0; j < 8; ++j) {
      aq = fmaf(r[j], Wqkv0[l8 * 8 + j], aq);
      ak = fmaf(r[j], Wqkv0[(8 + l8) * 8 + j], ak);
      av = fmaf(r[j], Wqkv0[(16 + l8) * 8 + j], av);
    }
    qs[c][l8] = aq * C_SCALE;
    ks[c][l8] = ak;
    vs[c][l8] = av;
  }
  __syncthreads();

  // ---- stage B: 32x32 exp table ----
  {
    const int qi = tid >> 3, l8 = tid & 7;
    float q[8];
#pragma unroll
    for (int j = 0; j < 8; ++j) q[j] = qs[qi][j];
#pragma unroll
    for (int jj = 0; jj < 4; ++jj) {
      const int ki = l8 + 8 * jj;
      float s0 = q[0] * ks[ki][0];
      s0 = fmaf(q[1], ks[ki][1], s0); s0 = fmaf(q[2], ks[ki][2], s0); s0 = fmaf(q[3], ks[ki][3], s0);
      float s1 = q[4] * ks[ki][4];
      s1 = fmaf(q[5], ks[ki][5], s1); s1 = fmaf(q[6], ks[ki][6], s1); s1 = fmaf(q[7], ks[ki][7], s1);
      ws[ET + qi * 33 + ki] = pkrtz(exp2_fast(s0), exp2_fast(s1));
    }
  }
  // ---- stage C: layer-0 v table, head-interleaved pairs ----
  if (tid < 32) {
#pragma unroll
    for (int p = 0; p < 4; ++p) ws[VT + tid * 4 + p] = pkrtz(vs[tid][p], vs[tid][p + 4]);
  }
}

__global__ __launch_bounds__(256, 8) void BetterBot_44169443672375_kernel(
    const int* __restrict__ dice_type, const int* __restrict__ dice_star,
    const int* __restrict__ summon_lvl,
    const h2* __restrict__ wp,
    float* __restrict__ out)
{
  __shared__ __align__(16) h2 tbl[1312];           // [xT 128 | vT 128 | eT 1056]
  __shared__ int idxT[EPB][16];
  __shared__ __align__(16) float kvb[EPB][15][12]; // [k f16 pairs (4 slots) | v f32 permuted (8)]

  const int tid = threadIdx.x;
  const int e = tid >> 4;       // element in block
  const int t = tid & 15;       // token (15 = pad lane)
  const int ge = blockIdx.x * EPB + e;
  const float* wsf = (const float*)wp;

  // ---- phase 1: global->LDS table copy + indices ----
  {
    float4* d = (float4*)tbl;
    const float4* s = (const float4*)(wp + TBL0);
    d[tid] = s[tid];
    if (tid < TBLV4 - 256) d[256 + tid] = s[256 + tid];
  }
  int myc = 0;
  if (t < 15) {
    int c;
    if (t < 5)       c = dice_type[ge * 5 + t];
    else if (t < 10) c = 15 + dice_star[ge * 5 + (t - 5)];
    else             c = 30 + summon_lvl[ge * 5 + (t - 10)];
    idxT[e][t] = c;
    myc = c;
  }
  __syncthreads();

  // ---- layer 0 (table-driven pk) + layer-1 qkv ----
  h2 x2[4] = {(h2)(_Float16)0.f, (h2)(_Float16)0.f, (h2)(_Float16)0.f, (h2)(_Float16)0.f};
  h2 q2[4];
  if (t < 15) {
    F4H2 xx; xx.f = *(const float4*)(&tbl[XTO + myc * 4]);
#pragma unroll
    for (int p = 0; p < 4; ++p) x2[p] = xx.h[p];

    h2 o2[4] = {(h2)(_Float16)0.f, (h2)(_Float16)0.f, (h2)(_Float16)0.f, (h2)(_Float16)0.f};
    h2 os2 = (h2)(_Float16)0.f;          // pk sums; table e <= ~2^5, sum <= ~500 << 65504
    const h2* myE = tbl + ETO + myc * 33;
    const int* myI = idxT[e];
#pragma unroll
    for (int u = 0; u < 15; ++u) {
      const int uc = myI[u];
      const h2 ee2 = myE[uc];
      F4H2 vv; vv.f = *(const float4*)(&tbl[VTO + uc * 4]);
      os2 += ee2;
      o2[0] += ee2 * vv.h[0];
      o2[1] += ee2 * vv.h[1];
      o2[2] += ee2 * vv.h[2];
      o2[3] += ee2 * vv.h[3];
    }
    const h2 rp2 = pkrtz(rcp_fast((float)os2.x), rcp_fast((float)os2.y));
#pragma unroll
    for (int p = 0; p < 4; ++p) o2[p] *= rp2;

    h2 y2[4], xn2[4], hh2[4];
    mm8_h2(wp, WO0, BO0, o2, y2);
#pragma unroll
    for (int p = 0; p < 4; ++p) xn2[p] = x2[p] + y2[p];
    mm8_h2(wp, WL0, BL0, xn2, hh2);
    const h2 z2 = (h2)(_Float16)0.f;
#pragma unroll
    for (int p = 0; p < 4; ++p) x2[p] = xn2[p] + __builtin_elementwise_max(hh2[p], z2);

    // layer-1 q,k (pk-f16) + v (f32 fdot2, permuted rows)
    h2 qkv2[8];
#pragma unroll
    for (int c2 = 0; c2 < 8; ++c2) {
      h2 acc = wp[BQKV1 + c2];
#pragma unroll
      for (int p = 0; p < 4; ++p) {
        acc += (h2)(x2[p].x) * wp[WQKV1 + c2 * 8 + 2 * p];
        acc += (h2)(x2[p].y) * wp[WQKV1 + c2 * 8 + 2 * p + 1];
      }
      qkv2[c2] = acc;
    }
#pragma unroll
    for (int p = 0; p < 4; ++p) q2[p] = qkv2[p];
    float vv[8];
#pragma unroll
    for (int r = 0; r < 8; ++r) {
      float acc = wsf[BV1F + r];
#pragma unroll
      for (int p = 0; p < 4; ++p) acc = fdot2f(x2[p], wp[WV1P + r * 4 + p], acc);
      vv[r] = acc;
    }
    F4H2 ka;
#pragma unroll
    for (int p = 0; p < 4; ++p) ka.h[p] = qkv2[4 + p];
    *(float4*)(&kvb[e][t][0]) = ka.f;
    *(float4*)(&kvb[e][t][4]) = make_float4(vv[0], vv[1], vv[2], vv[3]);
    *(float4*)(&kvb[e][t][8]) = make_float4(vv[4], vv[5], vv[6], vv[7]);
  }
  __syncthreads();

  // ---- layer 1: fdot2 f16 scores, f32 exp/sums/PV (overflow-safe, R8-proven) ----
  if (t < 15) {
    float o[8] = {0.f, 0.f, 0.f, 0.f, 0.f, 0.f, 0.f, 0.f};  // permuted order
    float sum0 = 0.f, sum1 = 0.f;
#pragma unroll
    for (int u = 0; u < 15; ++u) {
      F4H2 kk; kk.f = *(const float4*)(&kvb[e][u][0]);
      const float4 va = *(const float4*)(&kvb[e][u][4]);
      const float4 vb = *(const float4*)(&kvb[e][u][8]);
      const float s0 = fdot2f(q2[0], kk.h[0], fdot2f(q2[1], kk.h[1], 0.f));
      const float s1 = fdot2f(q2[2], kk.h[2], fdot2f(q2[3], kk.h[3], 0.f));
      const float e0 = exp2_fast(s0);
      const float e1 = exp2_fast(s1);
      sum0 += e0; sum1 += e1;
      o[0] = fmaf(e0, va.x, o[0]); o[1] = fmaf(e1, va.y, o[1]);
      o[2] = fmaf(e0, va.z, o[2]); o[3] = fmaf(e1, va.w, o[3]);
      o[4] = fmaf(e0, vb.x, o[4]); o[5] = fmaf(e1, vb.y, o[5]);
      o[6] = fmaf(e0, vb.z, o[6]); o[7] = fmaf(e1, vb.w, o[7]);
    }
    const float r0 = rcp_fast(sum0), r1 = rcp_fast(sum1);
    h2 po2[4];
#pragma unroll
    for (int i = 0; i < 4; ++i) po2[i] = pkrtz(o[2 * i] * r0, o[2 * i + 1] * r1);

    h2 y2[4], xn2[4], hh2[4];
    mm8_h2(wp, WO1, BO1, po2, y2);
#pragma unroll
    for (int p = 0; p < 4; ++p) xn2[p] = x2[p] + y2[p];
    mm8_h2(wp, WL1, BL1, xn2, hh2);
    const h2 z2 = (h2)(_Float16)0.f;
#pragma unroll
    for (int p = 0; p < 4; ++p) x2[p] = xn2[p] + __builtin_elementwise_max(hh2[p], z2);
  } else {
#pragma unroll
    for (int p = 0; p < 4; ++p) x2[p] = (h2)(_Float16)0.f;  // pad lane contributes 0
  }

  // ---- epilogue: token-sum via h2 butterfly; 1/15 pre-folded into Wout' ----
  h2 p2[4];
#pragma unroll
  for (int p = 0; p < 4; ++p) p2[p] = x2[p];
#pragma unroll
  for (int m = 1; m <= 8; m <<= 1) {
#pragma unroll
    for (int p = 0; p < 4; ++p) {
      H2I a; a.h = p2[p];
      H2I b; b.i = __shfl_xor(a.i, m);
      p2[p] += b.h;
    }
  }
  float sx[8];
#pragma unroll
  for (int i = 0; i < 4; ++i) { sx[2 * i] = (float)p2[i].x; sx[2 * i + 1] = (float)p2[i].y; }

  const int obase = ge * 20;
  {
    float acc = wsf[BOUTF + t];
#pragma unroll
    for (int j = 0; j < 8; ++j) acc = fmaf(sx[j], wsf[WOUTF + t * 8 + j], acc);
    out[obase + t] = acc;               // a = 0..15
  }
  if (t < 4) {
    const int a = 16 + t;
    float acc = wsf[BOUTF + a];
#pragma unroll
    for (int j = 0; j < 8; ++j) acc = fmaf(sx[j], wsf[WOUTF + a * 8 + j], acc);
    out[obase + a] = acc;               // a = 16..19
  }
}

extern "C" void kernel_launch(void* const* d_in, const int* in_sizes, int n_in,
                              void* d_out, int out_size, void* d_ws, size_t ws_size,
                              hipStream_t stream) {
  const int*   dice_type  = (const int*)d_in[0];
  const int*   dice_star  = (const int*)d_in[1];
  const int*   summon_lvl = (const int*)d_in[2];
  const float* emb_dice   = (const float*)d_in[3];
  const float* emb_star   = (const float*)d_in[4];
  const float* emb_btns   = (const float*)d_in[5];
  const float* Wout       = (const float*)d_in[6];
  const float* bout       = (const float*)d_in[7];
  const float* Wqkv0      = (const float*)d_in[8];
  const float* bqkv0      = (const float*)d_in[9];
  const float* Wo0        = (const float*)d_in[10];
  const float* bo0        = (const float*)d_in[11];
  const float* Wl0        = (const float*)d_in[12];
  const float* bl0        = (const float*)d_in[13];
  const float* Wqkv1      = (const float*)d_in[14];
  const float* bqkv1      = (const float*)d_in[15];
  const float* Wo1        = (const float*)d_in[16];
  const float* bo1        = (const float*)d_in[17];
  const float* Wl1        = (const float*)d_in[18];
  const float* bl1        = (const float*)d_in[19];
  float* out = (float*)d_out;
  h2* ws = (h2*)d_ws;

  hipLaunchKernelGGL(BetterBot_setup, dim3(1), dim3(256), 0, stream,
                     emb_dice, emb_star, emb_btns, Wout, bout,
                     Wqkv0, bqkv0, Wqkv1, bqkv1,
                     Wo0, bo0, Wl0, bl0, Wo1, bo1, Wl1, bl1, ws);
  hipLaunchKernelGGL(BetterBot_44169443672375_kernel, dim3(BTOT / EPB), dim3(256), 0, stream,
                     dice_type, dice_star, summon_lvl, (const h2*)ws, out);
}

// Round 10
// 120.720 us; speedup vs baseline: 1.0850x; 1.0203x over previous
//
#include <hip/hip_runtime.h>
#include <math.h>

// B=65536, D=8, H=2 (hd=4), S=15 tokens, A=20 outputs.
// R10: LDS-pipe diet on R9. (1) layer-1 kvb = [k 4xh2 | v 4xh2] 32B/token
// (v f16 -> 2 b128/key instead of 3; PV via fmaf(e,(float)vh,.) which folds
// to v_fma_mix_f32); (2) token indices packed into 4 bytes-regs via 6-shfl
// OR-tree, bfe per L0 iter (no idxT LDS); (3) kvb element stride 17*32B ->
// wave's 4 groups on disjoint bank quads. Layer-1 e/sum/PV stay f32 (the R7
// overflow lesson). Setup kernel identical to R9.
#define EPB 16
#define BTOT 65536
#define C_SCALE 0.72134752044f  // 0.5 * log2(e)

typedef _Float16 h2 __attribute__((ext_vector_type(2)));
typedef __fp16 fp16v2 __attribute__((ext_vector_type(2)));

// d_ws h2 layout offsets (h2 = 4B, same index granularity as float)
#define WQKV1 0     // 96: [c2=0..11][j pairs]; q rows (2c,2c+1)*C_SCALE, k rows seq
#define BQKV1 96    // 12
#define WO0   108   // 32: cols reordered (p, p+4) for interleaved-o input
#define BO0   140   // 4
#define WL0   144   // 32: natural
#define BL0   176   // 4
#define WO1   180   // 32: cols reordered
#define BO1   212   // 4
#define WL1   216   // 32: natural
#define BL1   248   // 4
#define WV1P  256   // 32: [r=0..7][p=0..3]; rows permuted v0,v4,v1,v5,v2,v6,v3,v7
#define BV1F  288   // 8 f32 biases (permuted)
#define XT    304   // 128: x rows, seq pairs
#define VT    432   // 128: layer-0 v rows, head-interleaved pairs (stride 4)
#define ET    560   // 1056: e[qi*33+ki] = (e_h0, e_h1) f16
#define WOUTF 1616  // 160 f32: Wout/15, [a][j]
#define BOUTF 1776  // 20 f32: bout
#define TBL0  304
#define TBLV4 328
#define XTO 0
#define VTO 128
#define ETO 256

__device__ __forceinline__ float exp2_fast(float x) { return __builtin_amdgcn_exp2f(x); }
__device__ __forceinline__ float rcp_fast(float x)  { return __builtin_amdgcn_rcpf(x); }
__device__ __forceinline__ h2 pkrtz(float a, float b) {
  fp16v2 r = __builtin_amdgcn_cvt_pkrtz(a, b);
  return __builtin_bit_cast(h2, r);
}
__device__ __forceinline__ float fdot2f(h2 a, h2 b, float c) {
#if defined(__has_builtin) && __has_builtin(__builtin_amdgcn_fdot2)
  return __builtin_amdgcn_fdot2(a, b, c, false);
#else
  return (float)a.x * (float)b.x + (float)a.y * (float)b.y + c;
#endif
}

union F4H2 { float4 f; h2 h[4]; };
union H2I { h2 h; int i; };

__device__ __forceinline__ void mm8_h2(const h2* __restrict__ wp, int woff, int boff,
                                       const h2 in2[4], h2 out2[4])
{
#pragma unroll
  for (int c2 = 0; c2 < 4; ++c2) {
    h2 acc = wp[boff + c2];
#pragma unroll
    for (int p = 0; p < 4; ++p) {
      acc += (h2)(in2[p].x) * wp[woff + c2 * 8 + 2 * p];
      acc += (h2)(in2[p].y) * wp[woff + c2 * 8 + 2 * p + 1];
    }
    out2[c2] = acc;
  }
}

__global__ void BetterBot_setup(
    const float* __restrict__ emb_dice, const float* __restrict__ emb_star,
    const float* __restrict__ emb_btns,
    const float* __restrict__ Wout, const float* __restrict__ bout,
    const float* __restrict__ Wqkv0, const float* __restrict__ bqkv0,
    const float* __restrict__ Wqkv1, const float* __restrict__ bqkv1,
    const float* __restrict__ Wo0, const float* __restrict__ bo0,
    const float* __restrict__ Wl0, const float* __restrict__ bl0,
    const float* __restrict__ Wo1, const float* __restrict__ bo1,
    const float* __restrict__ Wl1, const float* __restrict__ bl1,
    h2* __restrict__ ws)
{
  __shared__ float qs[32][8], ks[32][8], vs[32][8];
  const int tid = threadIdx.x;
  float* wsf = (float*)ws;

  if (tid < 96) {
    const int c2 = tid >> 3, j = tid & 7;
    int ra, rb; float s = 1.0f;
    if (c2 < 4)      { ra = 2 * c2; rb = ra + 1; s = C_SCALE; }
    else if (c2 < 8) { ra = 8 + 2 * (c2 - 4); rb = ra + 1; }
    else             { ra = 16 + (c2 - 8); rb = ra + 4; }
    ws[tid] = pkrtz(Wqkv1[ra * 8 + j] * s, Wqkv1[rb * 8 + j] * s);
  } else if (tid < 108) {
    const int c2 = tid - 96;
    int ra, rb; float s = 1.0f;
    if (c2 < 4)      { ra = 2 * c2; rb = ra + 1; s = C_SCALE; }
    else if (c2 < 8) { ra = 8 + 2 * (c2 - 4); rb = ra + 1; }
    else             { ra = 16 + (c2 - 8); rb = ra + 4; }
    ws[tid] = pkrtz(bqkv1[ra] * s, bqkv1[rb] * s);
  } else if (tid < 140) {
    const int k = tid - 108, c2 = k >> 3, j = k & 7, p = j >> 1;
    const int col = (j & 1) ? (p + 4) : p;
    ws[tid] = pkrtz(Wo0[(2 * c2) * 8 + col], Wo0[(2 * c2 + 1) * 8 + col]);
  } else if (tid < 144) {
    const int c2 = tid - 140;
    ws[tid] = pkrtz(bo0[2 * c2], bo0[2 * c2 + 1]);
  } else if (tid < 176) {
    const int k = tid - 144, c2 = k >> 3, j = k & 7;
    ws[tid] = pkrtz(Wl0[(2 * c2) * 8 + j], Wl0[(2 * c2 + 1) * 8 + j]);
  } else if (tid < 180) {
    const int c2 = tid - 176;
    ws[tid] = pkrtz(bl0[2 * c2], bl0[2 * c2 + 1]);
  } else if (tid < 212) {
    const int k = tid - 180, c2 = k >> 3, j = k & 7, p = j >> 1;
    const int col = (j & 1) ? (p + 4) : p;
    ws[tid] = pkrtz(Wo1[(2 * c2) * 8 + col], Wo1[(2 * c2 + 1) * 8 + col]);
  } else if (tid < 216) {
    const int c2 = tid - 212;
    ws[tid] = pkrtz(bo1[2 * c2], bo1[2 * c2 + 1]);
  } else if (tid < 248) {
    const int k = tid - 216, c2 = k >> 3, j = k & 7;
    ws[tid] = pkrtz(Wl1[(2 * c2) * 8 + j], Wl1[(2 * c2 + 1) * 8 + j]);
  } else if (tid < 252) {
    const int c2 = tid - 248;
    ws[tid] = pkrtz(bl1[2 * c2], bl1[2 * c2 + 1]);
  }
  if (tid < 32) {
    const int r = tid >> 2, p = tid & 3;
    const int row = 16 + (r >> 1) + (r & 1) * 4;   // perm: v0,v4,v1,v5,v2,v6,v3,v7
    ws[WV1P + tid] = pkrtz(Wqkv1[row * 8 + 2 * p], Wqkv1[row * 8 + 2 * p + 1]);
  } else if (tid < 40) {
    const int r = tid - 32;
    const int row = 16 + (r >> 1) + (r & 1) * 4;
    wsf[BV1F + r] = bqkv1[row];
  }
  if (tid < 160)      wsf[WOUTF + tid] = Wout[tid] * (1.0f / 15.0f);
  else if (tid < 180) wsf[BOUTF + tid - 160] = bout[tid - 160];

  {
    const int c = tid >> 3, l8 = tid & 7;
    const float* er;
    if (c < 15)      er = emb_dice + 8 * c;
    else if (c < 30) er = emb_star + 8 * (c - 15);
    else             er = emb_btns + 8 * (c - 30);
    const float4 r0 = ((const float4*)er)[0];
    const float4 r1 = ((const float4*)er)[1];
    float r[8] = {r0.x, r0.y, r0.z, r0.w, r1.x, r1.y, r1.z, r1.w};
    if (l8 < 4) ws[XT + c * 4 + l8] = pkrtz(r[2 * l8], r[2 * l8 + 1]);
    float aq = bqkv0[l8], ak = bqkv0[8 + l8], av = bqkv0[16 + l8];
#pragma unroll
    for (int j = 0; j < 8; ++j) {
      aq = fmaf(r[j], Wqkv0[l8 * 8 + j], aq);
      ak = fmaf(r[j], Wqkv0[(8 + l8) * 8 + j], ak);
      av = fmaf(r[j], Wqkv0[(16 + l8) * 8 + j], av);
    }
    qs[c][l8] = aq * C_SCALE;
    ks[c][l8] = ak;
    vs[c][l8] = av;
  }
  __syncthreads();

  {
    const int qi = tid >> 3, l8 = tid & 7;
    float q[8];
#pragma unroll
    for (int j = 0; j < 8; ++j) q[j] = qs[qi][j];
#pragma unroll
    for (int jj = 0; jj < 4; ++jj) {
      const int ki = l8 + 8 * jj;
      float s0 = q[0] * ks[ki][0];
      s0 = fmaf(q[1], ks[ki][1], s0); s0 = fmaf(q[2], ks[ki][2], s0); s0 = fmaf(q[3], ks[ki][3], s0);
      float s1 = q[4] * ks[ki][4];
      s1 = fmaf(q[5], ks[ki][5], s1); s1 = fmaf(q[6], ks[ki][6], s1); s1 = fmaf(q[7], ks[ki][7], s1);
      ws[ET + qi * 33 + ki] = pkrtz(exp2_fast(s0), exp2_fast(s1));
    }
  }
  if (tid < 32) {
#pragma unroll
    for (int p = 0; p < 4; ++p) ws[VT + tid * 4 + p] = pkrtz(vs[tid][p], vs[tid][p + 4]);
  }
}

__global__ __launch_bounds__(256, 8) void BetterBot_44169443672375_kernel(
    const int* __restrict__ dice_type, const int* __restrict__ dice_star,
    const int* __restrict__ summon_lvl,
    const h2* __restrict__ wp,
    float* __restrict__ out)
{
  __shared__ __align__(16) h2 tbl[1312];        // [xT 128 | vT 128 | eT 1056]
  __shared__ __align__(16) h2 kvb[EPB][17][8];  // token: [k 4xh2 | v 4xh2]; stride 17*32B

  const int tid = threadIdx.x;
  const int e = tid >> 4;       // element in block
  const int t = tid & 15;       // token (15 = pad lane)
  const int ge = blockIdx.x * EPB + e;
  const float* wsf = (const float*)wp;

  // ---- phase 1: global->LDS table copy + packed indices via shfl ----
  {
    float4* d = (float4*)tbl;
    const float4* s = (const float4*)(wp + TBL0);
    d[tid] = s[tid];
    if (tid < TBLV4 - 256) d[256 + tid] = s[256 + tid];
  }
  int myc = 0;
  if (t < 15) {
    if (t < 5)       myc = dice_type[ge * 5 + t];
    else if (t < 10) myc = 15 + dice_star[ge * 5 + (t - 5)];
    else             myc = 30 + summon_lvl[ge * 5 + (t - 10)];
  }
  // pack the group's 16 token indices into 4 byte-packed words (all lanes active)
  int W[4];
  {
    int wv = myc << (8 * (t & 3));
    wv |= __shfl_xor(wv, 1);
    wv |= __shfl_xor(wv, 2);
    const int gb = (tid & 63) & 48;   // group base within wave
#pragma unroll
    for (int k = 0; k < 4; ++k) W[k] = __shfl(wv, gb + 4 * k);
  }
  __syncthreads();

  // ---- layer 0 (table-driven pk) + layer-1 qkv ----
  h2 x2[4] = {(h2)(_Float16)0.f, (h2)(_Float16)0.f, (h2)(_Float16)0.f, (h2)(_Float16)0.f};
  h2 q2[4];
  if (t < 15) {
    F4H2 xx; xx.f = *(const float4*)(&tbl[XTO + myc * 4]);
#pragma unroll
    for (int p = 0; p < 4; ++p) x2[p] = xx.h[p];

    h2 o2[4] = {(h2)(_Float16)0.f, (h2)(_Float16)0.f, (h2)(_Float16)0.f, (h2)(_Float16)0.f};
    h2 os2 = (h2)(_Float16)0.f;          // pk sums; table e bounded (R9-proven)
    const h2* myE = tbl + ETO + myc * 33;
#pragma unroll
    for (int u = 0; u < 15; ++u) {
      const int uc = (W[u >> 2] >> (8 * (u & 3))) & 0xff;
      const h2 ee2 = myE[uc];
      F4H2 vv; vv.f = *(const float4*)(&tbl[VTO + uc * 4]);
      os2 += ee2;
      o2[0] += ee2 * vv.h[0];
      o2[1] += ee2 * vv.h[1];
      o2[2] += ee2 * vv.h[2];
      o2[3] += ee2 * vv.h[3];
    }
    const h2 rp2 = pkrtz(rcp_fast((float)os2.x), rcp_fast((float)os2.y));
#pragma unroll
    for (int p = 0; p < 4; ++p) o2[p] *= rp2;

    h2 y2[4], xn2[4], hh2[4];
    mm8_h2(wp, WO0, BO0, o2, y2);
#pragma unroll
    for (int p = 0; p < 4; ++p) xn2[p] = x2[p] + y2[p];
    mm8_h2(wp, WL0, BL0, xn2, hh2);
    const h2 z2 = (h2)(_Float16)0.f;
#pragma unroll
    for (int p = 0; p < 4; ++p) x2[p] = xn2[p] + __builtin_elementwise_max(hh2[p], z2);

    // layer-1 q,k (pk-f16) + v (f32 fdot2, permuted rows)
    h2 qkv2[8];
#pragma unroll
    for (int c2 = 0; c2 < 8; ++c2) {
      h2 acc = wp[BQKV1 + c2];
#pragma unroll
      for (int p = 0; p < 4; ++p) {
        acc += (h2)(x2[p].x) * wp[WQKV1 + c2 * 8 + 2 * p];
        acc += (h2)(x2[p].y) * wp[WQKV1 + c2 * 8 + 2 * p + 1];
      }
      qkv2[c2] = acc;
    }
#pragma unroll
    for (int p = 0; p < 4; ++p) q2[p] = qkv2[p];
    float vv[8];
#pragma unroll
    for (int r = 0; r < 8; ++r) {
      float acc = wsf[BV1F + r];
#pragma unroll
      for (int p = 0; p < 4; ++p) acc = fdot2f(x2[p], wp[WV1P + r * 4 + p], acc);
      vv[r] = acc;
    }
    F4H2 kw;
#pragma unroll
    for (int p = 0; p < 4; ++p) kw.h[p] = qkv2[4 + p];
    *(float4*)(&kvb[e][t][0]) = kw.f;
    F4H2 vw;                              // v as f16 pairs (bounded; e stays f32)
    vw.h[0] = pkrtz(vv[0], vv[1]);
    vw.h[1] = pkrtz(vv[2], vv[3]);
    vw.h[2] = pkrtz(vv[4], vv[5]);
    vw.h[3] = pkrtz(vv[6], vv[7]);
    *(float4*)(&kvb[e][t][4]) = vw.f;
  }
  __syncthreads();

  // ---- layer 1: fdot2 f16 scores, f32 exp/sums/PV (fma_mix on f16 v) ----
  if (t < 15) {
    float o[8] = {0.f, 0.f, 0.f, 0.f, 0.f, 0.f, 0.f, 0.f};  // permuted order
    float sum0 = 0.f, sum1 = 0.f;
#pragma unroll
    for (int u = 0; u < 15; ++u) {
      F4H2 kk; kk.f = *(const float4*)(&kvb[e][u][0]);
      F4H2 vh; vh.f = *(const float4*)(&kvb[e][u][4]);
      const float s0 = fdot2f(q2[0], kk.h[0], fdot2f(q2[1], kk.h[1], 0.f));
      const float s1 = fdot2f(q2[2], kk.h[2], fdot2f(q2[3], kk.h[3], 0.f));
      const float e0 = exp2_fast(s0);
      const float e1 = exp2_fast(s1);
      sum0 += e0; sum1 += e1;
      o[0] = fmaf(e0, (float)vh.h[0].x, o[0]);
      o[1] = fmaf(e1, (float)vh.h[0].y, o[1]);
      o[2] = fmaf(e0, (float)vh.h[1].x, o[2]);
      o[3] = fmaf(e1, (float)vh.h[1].y, o[3]);
      o[4] = fmaf(e0, (float)vh.h[2].x, o[4]);
      o[5] = fmaf(e1, (float)vh.h[2].y, o[5]);
      o[6] = fmaf(e0, (float)vh.h[3].x, o[6]);
      o[7] = fmaf(e1, (float)vh.h[3].y, o[7]);
    }
    const float r0 = rcp_fast(sum0), r1 = rcp_fast(sum1);
    h2 po2[4];
#pragma unroll
    for (int i = 0; i < 4; ++i) po2[i] = pkrtz(o[2 * i] * r0, o[2 * i + 1] * r1);

    h2 y2[4], xn2[4], hh2[4];
    mm8_h2(wp, WO1, BO1, po2, y2);
#pragma unroll
    for (int p = 0; p < 4; ++p) xn2[p] = x2[p] + y2[p];
    mm8_h2(wp, WL1, BL1, xn2, hh2);
    const h2 z2 = (h2)(_Float16)0.f;
#pragma unroll
    for (int p = 0; p < 4; ++p) x2[p] = xn2[p] + __builtin_elementwise_max(hh2[p], z2);
  } else {
#pragma unroll
    for (int p = 0; p < 4; ++p) x2[p] = (h2)(_Float16)0.f;  // pad lane contributes 0
  }

  // ---- epilogue: token-sum via h2 butterfly; 1/15 pre-folded into Wout' ----
  h2 p2[4];
#pragma unroll
  for (int p = 0; p < 4; ++p) p2[p] = x2[p];
#pragma unroll
  for (int m = 1; m <= 8; m <<= 1) {
#pragma unroll
    for (int p = 0; p < 4; ++p) {
      H2I a; a.h = p2[p];
      H2I b; b.i = __shfl_xor(a.i, m);
      p2[p] += b.h;
    }
  }
  float sx[8];
#pragma unroll
  for (int i = 0; i < 4; ++i) { sx[2 * i] = (float)p2[i].x; sx[2 * i + 1] = (float)p2[i].y; }

  const int obase = ge * 20;
  {
    float acc = wsf[BOUTF + t];
#pragma unroll
    for (int j = 0; j < 8; ++j) acc = fmaf(sx[j], wsf[WOUTF + t * 8 + j], acc);
    out[obase + t] = acc;               // a = 0..15
  }
  if (t < 4) {
    const int a = 16 + t;
    float acc = wsf[BOUTF + a];
#pragma unroll
    for (int j = 0; j < 8; ++j) acc = fmaf(sx[j], wsf[WOUTF + a * 8 + j], acc);
    out[obase + a] = acc;               // a = 16..19
  }
}

extern "C" void kernel_launch(void* const* d_in, const int* in_sizes, int n_in,
                              void* d_out, int out_size, void* d_ws, size_t ws_size,
                              hipStream_t stream) {
  const int*   dice_type  = (const int*)d_in[0];
  const int*   dice_star  = (const int*)d_in[1];
  const int*   summon_lvl = (const int*)d_in[2];
  const float* emb_dice   = (const float*)d_in[3];
  const float* emb_star   = (const float*)d_in[4];
  const float* emb_btns   = (const float*)d_in[5];
  const float* Wout       = (const float*)d_in[6];
  const float* bout       = (const float*)d_in[7];
  const float* Wqkv0      = (const float*)d_in[8];
  const float* bqkv0      = (const float*)d_in[9];
  const float* Wo0        = (const float*)d_in[10];
  const float* bo0        = (const float*)d_in[11];
  const float* Wl0        = (const float*)d_in[12];
  const float* bl0        = (const float*)d_in[13];
  const float* Wqkv1      = (const float*)d_in[14];
  const float* bqkv1      = (const float*)d_in[15];
  const float* Wo1        = (const float*)d_in[16];
  const float* bo1        = (const float*)d_in[17];
  const float* Wl1        = (const float*)d_in[18];
  const float* bl1        = (const float*)d_in[19];
  float* out = (float*)d_out;
  h2* ws = (h2*)d_ws;

  hipLaunchKernelGGL(BetterBot_setup, dim3(1), dim3(256), 0, stream,
                     emb_dice, emb_star, emb_btns, Wout, bout,
                     Wqkv0, bqkv0, Wqkv1, bqkv1,
                     Wo0, bo0, Wl0, bl0, Wo1, bo1, Wl1, bl1, ws);
  hipLaunchKernelGGL(BetterBot_44169443672375_kernel, dim3(BTOT / EPB), dim3(256), 0, stream,
                     dice_type, dice_star, summon_lvl, (const h2*)ws, out);
}